// Round 1
// baseline (1376.349 us; speedup 1.0000x reference)
//
#include <hip/hip_runtime.h>
#include <math.h>

#define CLS 128  // number of classes (C in the reference)

// ---------------------------------------------------------------------------
// Kernel 1: find segment starts. bag[] is sorted & contiguous (0..M-1, each
// nonempty). starts[m] = first index of bag m; starts[M] = N.
// ---------------------------------------------------------------------------
__global__ __launch_bounds__(256) void find_starts_kernel(
    const int* __restrict__ bag, int* __restrict__ starts, int N, int M) {
    int i = blockIdx.x * blockDim.x + threadIdx.x;
    if (i >= N) return;
    if (i == 0) {
        starts[bag[0]] = 0;
        starts[M] = N;
    } else if (bag[i] != bag[i - 1]) {
        starts[bag[i]] = i;
    }
}

// ---------------------------------------------------------------------------
// Kernel 2: one block (128 threads = 2 waves) per bag.
// Thread c owns class c: max over the bag's rows (coalesced: each row is a
// contiguous 512B segment covered by the block's 2 waves). Then an in-block
// logsumexp over the 128 class maxima and the per-bag loss.
// ---------------------------------------------------------------------------
__global__ __launch_bounds__(CLS) void bag_loss_kernel(
    const float* __restrict__ input, const int* __restrict__ target,
    const int* __restrict__ starts, float* __restrict__ losses) {
    const int m = blockIdx.x;
    const int c = threadIdx.x;
    const int s = starts[m];
    const int e = starts[m + 1];

    float mx = -INFINITY;
    const float* p = input + (size_t)s * CLS + c;
    for (int i = s; i < e; ++i, p += CLS) {
        mx = fmaxf(mx, *p);
    }

    __shared__ float vals[CLS];  // per-class bag maxima (need vals[target])
    __shared__ float red[CLS];   // reduction scratch
    vals[c] = mx;
    red[c] = mx;
    __syncthreads();

    // tree max over 128 classes
    #pragma unroll
    for (int off = CLS / 2; off > 0; off >>= 1) {
        if (c < off) red[c] = fmaxf(red[c], red[c + off]);
        __syncthreads();
    }
    const float bigmax = red[0];
    __syncthreads();

    // sum of exp(x - max)
    red[c] = expf(vals[c] - bigmax);
    __syncthreads();
    #pragma unroll
    for (int off = CLS / 2; off > 0; off >>= 1) {
        if (c < off) red[c] += red[c + off];
        __syncthreads();
    }

    if (c == 0) {
        const float logz = bigmax + logf(red[0]);
        losses[m] = logz - vals[target[m]];
    }
}

// ---------------------------------------------------------------------------
// Kernel 3a/3b: deterministic two-stage mean over M losses.
// ---------------------------------------------------------------------------
__global__ __launch_bounds__(256) void reduce_partial_kernel(
    const float* __restrict__ losses, float* __restrict__ partials, int M) {
    __shared__ float sm[256];
    float s = 0.f;
    for (int i = blockIdx.x * 256 + threadIdx.x; i < M; i += gridDim.x * 256)
        s += losses[i];
    sm[threadIdx.x] = s;
    __syncthreads();
    #pragma unroll
    for (int off = 128; off > 0; off >>= 1) {
        if (threadIdx.x < off) sm[threadIdx.x] += sm[threadIdx.x + off];
        __syncthreads();
    }
    if (threadIdx.x == 0) partials[blockIdx.x] = sm[0];
}

__global__ __launch_bounds__(256) void reduce_final_kernel(
    const float* __restrict__ partials, float* __restrict__ out, float invM) {
    __shared__ float sm[256];
    sm[threadIdx.x] = partials[threadIdx.x];
    __syncthreads();
    #pragma unroll
    for (int off = 128; off > 0; off >>= 1) {
        if (threadIdx.x < off) sm[threadIdx.x] += sm[threadIdx.x + off];
        __syncthreads();
    }
    if (threadIdx.x == 0) out[0] = sm[0] * invM;
}

extern "C" void kernel_launch(void* const* d_in, const int* in_sizes, int n_in,
                              void* d_out, int out_size, void* d_ws, size_t ws_size,
                              hipStream_t stream) {
    const float* input  = (const float*)d_in[0];  // [N, C] f32
    const int*   target = (const int*)d_in[1];    // [M] i32
    const int*   bag    = (const int*)d_in[2];    // [N] i32, sorted contiguous
    const int M = in_sizes[1];
    const int N = in_sizes[2];
    float* out = (float*)d_out;

    // workspace layout: starts[M+1] ints | losses[M] floats | partials[256]
    char* ws = (char*)d_ws;
    int* starts = (int*)ws;
    size_t off = ((size_t)(M + 1) * sizeof(int) + 255) & ~(size_t)255;
    float* losses = (float*)(ws + off);
    off += ((size_t)M * sizeof(float) + 255) & ~(size_t)255;
    float* partials = (float*)(ws + off);

    find_starts_kernel<<<(N + 255) / 256, 256, 0, stream>>>(bag, starts, N, M);
    bag_loss_kernel<<<M, CLS, 0, stream>>>(input, target, starts, losses);
    reduce_partial_kernel<<<256, 256, 0, stream>>>(losses, partials, M);
    reduce_final_kernel<<<1, 256, 0, stream>>>(partials, out, 1.0f / M);
}